// Round 1
// baseline (25.748 us; speedup 1.0000x reference)
//
#include <hip/hip_runtime.h>

// FocalLoss (sigmoid focal, mean reduction) for
//   cls_score: [N=4, C=19, H=512, W=512] float32
//   label:     [N=4, H=512, W=512] int32
// out: scalar float32 = mean over N*C*H*W of bce_with_logits(x, onehot) * focal_w * valid
//
// Memory-bound: ~84 MB read, 4 B write. Two-stage deterministic reduction
// (per-block partials in d_ws, then one-block finalize). No atomics.

#define NC 19
#define IGNORE_INDEX 255
#define ALPHA 0.25f

constexpr int NBATCH = 4;
constexpr int HW = 512 * 512;               // 262144 pixels per image plane
constexpr int QPP = HW / 4;                 // quads per plane = 65536
constexpr int NQUADS = NBATCH * QPP;        // 262144 total quads
constexpr int BLOCK = 256;
constexpr int GRID = NQUADS / BLOCK;        // 1024 blocks, exact
constexpr float INV_TOTAL = 1.0f / (float)(NBATCH * NC * HW);  // 1/19922944

__device__ __forceinline__ float block_reduce(float v, float* smem) {
    // wave64 butterfly-free down-reduce
    #pragma unroll
    for (int off = 32; off > 0; off >>= 1)
        v += __shfl_down(v, off, 64);
    const int lane = threadIdx.x & 63;
    const int wid  = threadIdx.x >> 6;
    if (lane == 0) smem[wid] = v;
    __syncthreads();
    float s = 0.0f;
    if (threadIdx.x == 0) {
        const int nw = blockDim.x >> 6;
        for (int i = 0; i < nw; ++i) s += smem[i];
    }
    return s;  // valid in thread 0 only
}

__global__ __launch_bounds__(BLOCK) void focal_partial(
        const float* __restrict__ x,
        const int*   __restrict__ label,
        float*       __restrict__ partial) {
    const int q = blockIdx.x * blockDim.x + threadIdx.x;   // quad index
    const int n  = q / QPP;
    const int pq = q - n * QPP;

    const int4 l4 = *reinterpret_cast<const int4*>(label + (size_t)n * HW + (size_t)pq * 4);
    int   lab[4]   = {l4.x, l4.y, l4.z, l4.w};
    bool  valid[4];
    #pragma unroll
    for (int j = 0; j < 4; ++j)
        valid[j] = (lab[j] >= 0) && (lab[j] != IGNORE_INDEX);

    const float* base = x + (size_t)n * NC * HW + (size_t)pq * 4;

    float acc = 0.0f;
    for (int c = 0; c < NC; ++c) {
        const float4 v = *reinterpret_cast<const float4*>(base + (size_t)c * HW);
        float xs[4] = {v.x, v.y, v.z, v.w};
        #pragma unroll
        for (int j = 0; j < 4; ++j) {
            if (valid[j]) {
                const float xv = xs[j];
                const bool  t  = (lab[j] == c);
                const float d  = t ? (1.0f - xv) : xv;
                const float w  = ALPHA * d * d;
                // bce_with_logits: max(x,0) - x*t + log1p(exp(-|x|))
                const float sp  = __logf(1.0f + __expf(-fabsf(xv)));
                const float bce = fmaxf(xv, 0.0f) - (t ? xv : 0.0f) + sp;
                acc += bce * w;
            }
        }
    }

    __shared__ float smem[BLOCK / 64];
    const float s = block_reduce(acc, smem);
    if (threadIdx.x == 0) partial[blockIdx.x] = s;
}

__global__ __launch_bounds__(BLOCK) void focal_finalize(
        const float* __restrict__ partial,
        float*       __restrict__ out) {
    float acc = 0.0f;
    for (int i = threadIdx.x; i < GRID; i += BLOCK)
        acc += partial[i];
    __shared__ float smem[BLOCK / 64];
    const float s = block_reduce(acc, smem);
    if (threadIdx.x == 0) out[0] = s * INV_TOTAL;  // LOSS_WEIGHT == 1.0
}

extern "C" void kernel_launch(void* const* d_in, const int* in_sizes, int n_in,
                              void* d_out, int out_size, void* d_ws, size_t ws_size,
                              hipStream_t stream) {
    const float* cls_score = (const float*)d_in[0];
    const int*   label     = (const int*)d_in[1];
    float* out     = (float*)d_out;
    float* partial = (float*)d_ws;

    focal_partial<<<GRID, BLOCK, 0, stream>>>(cls_score, label, partial);
    focal_finalize<<<1, BLOCK, 0, stream>>>(partial, out);
}